// Round 6
// baseline (817.015 us; speedup 1.0000x reference)
//
#include <hip/hip_runtime.h>

// GCN, gather formulation v5 — feature-sliced, XCD-pinned gather.
//   h stored slice-major: hs[s][node][8] (8 slices x 3.2 MB); slice = blockIdx%8
//   = XCD id (round-robin dispatch) -> each XCD's random gather works on a
//   3.2 MB slice that fits its 4 MB L2. Index stream read via nontemporal
//   loads so it doesn't evict the slice; output via nontemporal stores.
//   CSR build (counting sort, parallel scan) unchanged from v4.

#define FDIM 64
#define NPART 8          // node partitions for deg histogram
#define GPB 64           // blocks per partition
#define NB 256           // edge chunks for counting sort
#define BW 512           // cols per coarse bucket (1<<9)
#define MAXP 1024        // max coarse buckets supported

// --- degree histogram by row, LDS-partitioned: part[(p*GPB+g)*psize + local] ---
__global__ void k_deg(const int* __restrict__ row, unsigned* __restrict__ part,
                      int E, int n, int psize) {
    __shared__ unsigned sh[12512];           // >= psize = ceil(100000/8)
    int p = blockIdx.x / GPB;
    int g = blockIdx.x % GPB;
    int base = p * psize;
    int lim = n - base; if (lim > psize) lim = psize;
    for (int i = threadIdx.x; i < lim; i += blockDim.x) sh[i] = 0u;
    __syncthreads();
    int stride = GPB * blockDim.x;
    for (int e = g * blockDim.x + threadIdx.x; e < E; e += stride) {
        int r = row[e] - base;
        if ((unsigned)r < (unsigned)lim) atomicAdd(&sh[r], 1u);
    }
    __syncthreads();
    unsigned* dst = part + ((size_t)p * GPB + g) * psize;
    for (int i = threadIdx.x; i < lim; i += blockDim.x) dst[i] = sh[i];
}

__global__ void k_dis(const unsigned* __restrict__ part, float* __restrict__ dis,
                      int n, int psize) {
    int i = blockIdx.x * blockDim.x + threadIdx.x;
    if (i >= n) return;
    int p = i / psize, loc = i - p * psize;
    const unsigned* src = part + (size_t)p * GPB * psize + loc;
    unsigned s = 0;
    #pragma unroll 8
    for (int g = 0; g < GPB; ++g) s += src[(size_t)g * psize];
    dis[i] = rsqrtf((float)s + 1.0f);        // +1 = self loop
}

// --- coarse histogram: M[p*NB + b] = #edges in chunk b with col>>9 == p ---
__global__ void k_chist(const int* __restrict__ col, int* __restrict__ M,
                        int E, int CH, int P) {
    __shared__ int h[MAXP];
    int b = blockIdx.x;
    for (int i = threadIdx.x; i < P; i += blockDim.x) h[i] = 0;
    __syncthreads();
    int s = b * CH, e = min(s + CH, E);
    for (int i = s + threadIdx.x; i < e; i += blockDim.x)
        atomicAdd(&h[col[i] >> 9], 1);
    __syncthreads();
    for (int p = threadIdx.x; p < P; p += blockDim.x)
        M[p * NB + b] = h[p];
}

// --- 3-phase parallel exclusive scan of M[total] (bucket-major) ---
__global__ void k_s1(int* __restrict__ M, int* __restrict__ bsum, int total) {
    __shared__ int tmp[256];
    int t = threadIdx.x;
    int i = blockIdx.x * 256 + t;
    int v = (i < total) ? M[i] : 0;
    tmp[t] = v;
    __syncthreads();
    for (int d = 1; d < 256; d <<= 1) {
        int u = (t >= d) ? tmp[t - d] : 0;
        __syncthreads();
        tmp[t] += u;
        __syncthreads();
    }
    if (i < total) M[i] = tmp[t] - v;        // exclusive within block
    if (t == 255) bsum[blockIdx.x] = tmp[255];
}

__global__ void k_s2(int* __restrict__ bsum, int nb) {     // nb <= 256
    __shared__ int tmp[256];
    int t = threadIdx.x;
    int v = (t < nb) ? bsum[t] : 0;
    tmp[t] = v;
    __syncthreads();
    for (int d = 1; d < 256; d <<= 1) {
        int u = (t >= d) ? tmp[t - d] : 0;
        __syncthreads();
        tmp[t] += u;
        __syncthreads();
    }
    if (t < nb) bsum[t] = tmp[t] - v;        // exclusive
}

__global__ void k_s3(int* __restrict__ M, const int* __restrict__ bsum,
                     int total, int E) {
    int i = blockIdx.x * 256 + threadIdx.x;
    if (i < total) M[i] += bsum[blockIdx.x];
    if (i == 0) M[total] = E;                // sentinel
}

// --- deterministic coarse scatter: s8[pos] = {row,col}, grouped by bucket ---
__global__ void k_cscatter(const int* __restrict__ row, const int* __restrict__ col,
                           const int* __restrict__ M, int2* __restrict__ s8,
                           int E, int CH, int P) {
    __shared__ int cur[MAXP];
    int b = blockIdx.x;
    for (int p = threadIdx.x; p < P; p += blockDim.x) cur[p] = M[p * NB + b];
    __syncthreads();
    int s = b * CH, e = min(s + CH, E);
    for (int i = s + threadIdx.x; i < e; i += blockDim.x) {
        int r = row[i], c = col[i];
        int pos = atomicAdd(&cur[c >> 9], 1);  // LDS atomic
        s8[pos] = make_int2(r, c);
    }
}

// --- fine sort within bucket: true CSR off[n+1] + rows4[E] ---
__global__ void k_fsort(const int2* __restrict__ s8, const int* __restrict__ M,
                        int* __restrict__ rows4, int* __restrict__ off,
                        int n, int E, int P) {
    __shared__ int hist[BW];
    __shared__ int loff[BW];
    __shared__ int tmp[256];
    int p = blockIdx.x, t = threadIdx.x;
    int gs = M[p * NB];
    int ge = (p + 1 < P) ? M[(p + 1) * NB] : E;
    int c0 = p << 9;
    int lim = n - c0; if (lim > BW) lim = BW;
    hist[2 * t] = 0; hist[2 * t + 1] = 0;
    __syncthreads();
    for (int i = gs + t; i < ge; i += 256)
        atomicAdd(&hist[s8[i].y - c0], 1);
    __syncthreads();
    int s0 = hist[2 * t], s1 = hist[2 * t + 1];
    int ps = s0 + s1;
    tmp[t] = ps;
    __syncthreads();
    for (int d = 1; d < 256; d <<= 1) {
        int u = (t >= d) ? tmp[t - d] : 0;
        __syncthreads();
        tmp[t] += u;
        __syncthreads();
    }
    int ex = tmp[t] - ps;                    // exclusive over pairs
    loff[2 * t] = ex;
    loff[2 * t + 1] = ex + s0;
    __syncthreads();
    for (int i = t; i < lim; i += 256) off[c0 + i] = gs + loff[i];
    if (p == P - 1 && t == 0) off[n] = E;
    __syncthreads();
    for (int i = gs + t; i < ge; i += 256) {
        int2 rc = s8[i];
        int pos = gs + atomicAdd(&loff[rc.y - c0], 1);  // LDS atomic cursor
        rows4[pos] = rc.x;
    }
}

// --- gather, feature-sliced: slice s = blockIdx%8 (XCD-pinned), 8 lanes/node ---
template <bool RELU>
__global__ void k_gather(const int* __restrict__ rows4, const int* __restrict__ off,
                         const float* __restrict__ dis, const float* __restrict__ hs,
                         float* __restrict__ out, int n) {
    int s = blockIdx.x & 7;
    int g = threadIdx.x >> 3;                 // node within block (0..31)
    int f = threadIdx.x & 7;                  // feature within slice
    int w = (blockIdx.x >> 3) * 32 + g;
    if (w >= n) return;
    const float* slice = hs + (size_t)s * n * 8;
    float dc = dis[w];
    float acc = dc * dc * slice[(size_t)w * 8 + f];   // self loop
    int k = off[w], e = off[w + 1];
    for (; k + 4 <= e; k += 4) {
        int r0 = __builtin_nontemporal_load(rows4 + k);
        int r1 = __builtin_nontemporal_load(rows4 + k + 1);
        int r2 = __builtin_nontemporal_load(rows4 + k + 2);
        int r3 = __builtin_nontemporal_load(rows4 + k + 3);
        float h0 = slice[(size_t)r0 * 8 + f];
        float h1 = slice[(size_t)r1 * 8 + f];
        float h2 = slice[(size_t)r2 * 8 + f];
        float h3 = slice[(size_t)r3 * 8 + f];
        acc = fmaf(dis[r0] * dc, h0, acc);
        acc = fmaf(dis[r1] * dc, h1, acc);
        acc = fmaf(dis[r2] * dc, h2, acc);
        acc = fmaf(dis[r3] * dc, h3, acc);
    }
    for (; k < e; ++k) {
        int r = __builtin_nontemporal_load(rows4 + k);
        acc = fmaf(dis[r] * dc, slice[(size_t)r * 8 + f], acc);
    }
    if (RELU) acc = fmaxf(acc, 0.0f);
    __builtin_nontemporal_store(acc, out + (size_t)w * FDIM + s * 8 + f);
}

// --- linear layers; SLICED=true stores hs[j>>3][node][j&7] for the gather ---
__global__ void k_lin_concat(const float* __restrict__ x, const float* __restrict__ feat,
                             const float* __restrict__ W, const float* __restrict__ b,
                             float* __restrict__ out, int n) {
    __shared__ float sW[FDIM * FDIM];
    __shared__ float sIn[4][FDIM];
    int t = threadIdx.x;
    for (int i = t; i < FDIM * FDIM; i += 256) sW[i] = W[i];
    __syncthreads();
    int local = t >> 6, j = t & 63;
    float bj = b[j];
    size_t so = ((size_t)(j >> 3) * n) * 8 + (j & 7);
    for (int base = blockIdx.x * 4; base < n; base += gridDim.x * 4) {
        int node = base + local;
        if (node < n) {
            sIn[local][j] = (j < 32) ? x[(size_t)node * 32 + j]
                                     : feat[(size_t)node * 32 + (j - 32)];
            float acc = bj;
            #pragma unroll
            for (int k = 0; k < FDIM; ++k) acc = fmaf(sIn[local][k], sW[k * FDIM + j], acc);
            out[so + (size_t)node * 8] = acc;
        }
    }
}

template <bool RELU_OUT, bool SLICED>
__global__ void k_lin(const float* __restrict__ in, const float* __restrict__ W,
                      const float* __restrict__ b, float* __restrict__ out, int n) {
    __shared__ float sW[FDIM * FDIM];
    __shared__ float sIn[4][FDIM];
    int t = threadIdx.x;
    for (int i = t; i < FDIM * FDIM; i += 256) sW[i] = W[i];
    __syncthreads();
    int local = t >> 6, j = t & 63;
    float bj = b[j];
    size_t so = ((size_t)(j >> 3) * n) * 8 + (j & 7);
    for (int base = blockIdx.x * 4; base < n; base += gridDim.x * 4) {
        int node = base + local;
        if (node < n) {
            sIn[local][j] = in[(size_t)node * FDIM + j];
            float acc = bj;
            #pragma unroll
            for (int k = 0; k < FDIM; ++k) acc = fmaf(sIn[local][k], sW[k * FDIM + j], acc);
            if (RELU_OUT) acc = fmaxf(acc, 0.0f);
            if (SLICED) out[so + (size_t)node * 8] = acc;
            else        out[(size_t)node * FDIM + j] = acc;
        }
    }
}

extern "C" void kernel_launch(void* const* d_in, const int* in_sizes, int n_in,
                              void* d_out, int out_size, void* d_ws, size_t ws_size,
                              hipStream_t stream) {
    const float* x    = (const float*)d_in[0];
    const float* feat = (const float*)d_in[1];
    const int*   ei   = (const int*)d_in[2];
    const float* W1   = (const float*)d_in[3];
    const float* b1   = (const float*)d_in[4];
    const float* W2   = (const float*)d_in[5];
    const float* b2   = (const float*)d_in[6];
    const float* Wfc  = (const float*)d_in[7];
    const float* bfc  = (const float*)d_in[8];
    float* out = (float*)d_out;

    const int n = in_sizes[0] / 32;   // 100000
    const int E = in_sizes[2] / 2;    // 1600000
    const int* row = ei;
    const int* col = ei + E;

    const int psize = (n + NPART - 1) / NPART;   // 12500
    const int P  = (n + BW - 1) / BW;            // 196 coarse buckets
    const int CH = (E + NB - 1) / NB;            // 6250 edges per chunk
    const int total = P * NB;                    // 50176
    const int nb1 = (total + 255) / 256;         // 196 <= 256

    // ws (ints): off[n+1] | dis[n] | M[total+1] | bsum[256] | pad | s8[2E] |
    //            rows4[E] | bufA[64n] | bufB[64n]; part aliases bufA/bufB.
    int*   off  = (int*)d_ws;
    float* dis  = (float*)(off + (size_t)n + 1);
    int*   M    = (int*)(dis + n);
    int*   bsum = M + (size_t)total + 1;
    size_t co   = (size_t)n + 1 + n + total + 1 + 256;
    co += (co & 1);                              // int2 align
    int2*  s8    = (int2*)((int*)d_ws + co);
    int*   rows4 = (int*)(s8 + E);
    float* bufA  = (float*)(rows4 + E);
    float* bufB  = bufA + (size_t)n * FDIM;
    unsigned* part = (unsigned*)bufA;            // consumed by k_dis before lins

    const int B = 256;
    const int gGather = 8 * ((n + 31) / 32);     // slice = blockIdx%8 (XCD)

    // dis (deg by row)
    k_deg<<<NPART * GPB, B, 0, stream>>>(row, part, E, n, psize);
    k_dis<<<(n + B - 1) / B, B, 0, stream>>>(part, dis, n, psize);
    // CSR by col (deterministic counting sort, parallel scan)
    k_chist<<<NB, B, 0, stream>>>(col, M, E, CH, P);
    k_s1<<<nb1, B, 0, stream>>>(M, bsum, total);
    k_s2<<<1, B, 0, stream>>>(bsum, nb1);
    k_s3<<<nb1, B, 0, stream>>>(M, bsum, total, E);
    k_cscatter<<<NB, B, 0, stream>>>(row, col, M, s8, E, CH, P);
    k_fsort<<<P, B, 0, stream>>>(s8, M, rows4, off, n, E, P);

    // layer 1
    k_lin_concat<<<512, B, 0, stream>>>(x, feat, W1, b1, bufA, n);
    k_gather<true><<<gGather, B, 0, stream>>>(rows4, off, dis, bufA, bufB, n);
    // layer 2
    k_lin<false, true><<<512, B, 0, stream>>>(bufB, W2, b2, bufA, n);
    k_gather<true><<<gGather, B, 0, stream>>>(rows4, off, dis, bufA, bufB, n);
    // fc
    k_lin<true, false><<<512, B, 0, stream>>>(bufB, Wfc, bfc, out, n);
}

// Round 7
// 407.677 us; speedup vs baseline: 2.0041x; 2.0041x over previous
//
#include <hip/hip_runtime.h>

// GCN v6 — fused gather+matvec, register-resident W columns.
//   build (counting-sort CSR by col, parallel scan): unchanged from v4.
//   k_linc: t1 = concat(x,feat)@W1+b1          (persistent waves, W1 in VGPRs)
//   k_fused<false>: t2 = relu(agg(t1))@W2+b2   (gather + LDS-transpose + matvec)
//   k_fused<true>:  out = relu(relu(agg(t2))@Wfc+bfc)
// Matvec per node: 16 ds_read_b128 (sIn broadcast) + 64 FMA; W never in LDS.

#define FDIM 64
#define NPART 8
#define GPB 64
#define NB 256
#define BW 512
#define MAXP 1024

// --- degree histogram by row, LDS-partitioned ---
__global__ void k_deg(const int* __restrict__ row, unsigned* __restrict__ part,
                      int E, int n, int psize) {
    __shared__ unsigned sh[12512];
    int p = blockIdx.x / GPB;
    int g = blockIdx.x % GPB;
    int base = p * psize;
    int lim = n - base; if (lim > psize) lim = psize;
    for (int i = threadIdx.x; i < lim; i += blockDim.x) sh[i] = 0u;
    __syncthreads();
    int stride = GPB * blockDim.x;
    for (int e = g * blockDim.x + threadIdx.x; e < E; e += stride) {
        int r = row[e] - base;
        if ((unsigned)r < (unsigned)lim) atomicAdd(&sh[r], 1u);
    }
    __syncthreads();
    unsigned* dst = part + ((size_t)p * GPB + g) * psize;
    for (int i = threadIdx.x; i < lim; i += blockDim.x) dst[i] = sh[i];
}

__global__ void k_dis(const unsigned* __restrict__ part, float* __restrict__ dis,
                      int n, int psize) {
    int i = blockIdx.x * blockDim.x + threadIdx.x;
    if (i >= n) return;
    int p = i / psize, loc = i - p * psize;
    const unsigned* src = part + (size_t)p * GPB * psize + loc;
    unsigned s = 0;
    #pragma unroll 8
    for (int g = 0; g < GPB; ++g) s += src[(size_t)g * psize];
    dis[i] = rsqrtf((float)s + 1.0f);
}

// --- coarse histogram ---
__global__ void k_chist(const int* __restrict__ col, int* __restrict__ M,
                        int E, int CH, int P) {
    __shared__ int h[MAXP];
    int b = blockIdx.x;
    for (int i = threadIdx.x; i < P; i += blockDim.x) h[i] = 0;
    __syncthreads();
    int s = b * CH, e = min(s + CH, E);
    for (int i = s + threadIdx.x; i < e; i += blockDim.x)
        atomicAdd(&h[col[i] >> 9], 1);
    __syncthreads();
    for (int p = threadIdx.x; p < P; p += blockDim.x)
        M[p * NB + b] = h[p];
}

// --- 3-phase parallel exclusive scan ---
__global__ void k_s1(int* __restrict__ M, int* __restrict__ bsum, int total) {
    __shared__ int tmp[256];
    int t = threadIdx.x;
    int i = blockIdx.x * 256 + t;
    int v = (i < total) ? M[i] : 0;
    tmp[t] = v;
    __syncthreads();
    for (int d = 1; d < 256; d <<= 1) {
        int u = (t >= d) ? tmp[t - d] : 0;
        __syncthreads();
        tmp[t] += u;
        __syncthreads();
    }
    if (i < total) M[i] = tmp[t] - v;
    if (t == 255) bsum[blockIdx.x] = tmp[255];
}

__global__ void k_s2(int* __restrict__ bsum, int nb) {
    __shared__ int tmp[256];
    int t = threadIdx.x;
    int v = (t < nb) ? bsum[t] : 0;
    tmp[t] = v;
    __syncthreads();
    for (int d = 1; d < 256; d <<= 1) {
        int u = (t >= d) ? tmp[t - d] : 0;
        __syncthreads();
        tmp[t] += u;
        __syncthreads();
    }
    if (t < nb) bsum[t] = tmp[t] - v;
}

__global__ void k_s3(int* __restrict__ M, const int* __restrict__ bsum,
                     int total, int E) {
    int i = blockIdx.x * 256 + threadIdx.x;
    if (i < total) M[i] += bsum[blockIdx.x];
    if (i == 0) M[total] = E;
}

// --- deterministic coarse scatter ---
__global__ void k_cscatter(const int* __restrict__ row, const int* __restrict__ col,
                           const int* __restrict__ M, int2* __restrict__ s8,
                           int E, int CH, int P) {
    __shared__ int cur[MAXP];
    int b = blockIdx.x;
    for (int p = threadIdx.x; p < P; p += blockDim.x) cur[p] = M[p * NB + b];
    __syncthreads();
    int s = b * CH, e = min(s + CH, E);
    for (int i = s + threadIdx.x; i < e; i += blockDim.x) {
        int r = row[i], c = col[i];
        int pos = atomicAdd(&cur[c >> 9], 1);
        s8[pos] = make_int2(r, c);
    }
}

// --- fine sort -> off[n+1], rows4[E] ---
__global__ void k_fsort(const int2* __restrict__ s8, const int* __restrict__ M,
                        int* __restrict__ rows4, int* __restrict__ off,
                        int n, int E, int P) {
    __shared__ int hist[BW];
    __shared__ int loff[BW];
    __shared__ int tmp[256];
    int p = blockIdx.x, t = threadIdx.x;
    int gs = M[p * NB];
    int ge = (p + 1 < P) ? M[(p + 1) * NB] : E;
    int c0 = p << 9;
    int lim = n - c0; if (lim > BW) lim = BW;
    hist[2 * t] = 0; hist[2 * t + 1] = 0;
    __syncthreads();
    for (int i = gs + t; i < ge; i += 256)
        atomicAdd(&hist[s8[i].y - c0], 1);
    __syncthreads();
    int s0 = hist[2 * t], s1 = hist[2 * t + 1];
    int ps = s0 + s1;
    tmp[t] = ps;
    __syncthreads();
    for (int d = 1; d < 256; d <<= 1) {
        int u = (t >= d) ? tmp[t - d] : 0;
        __syncthreads();
        tmp[t] += u;
        __syncthreads();
    }
    int ex = tmp[t] - ps;
    loff[2 * t] = ex;
    loff[2 * t + 1] = ex + s0;
    __syncthreads();
    for (int i = t; i < lim; i += 256) off[c0 + i] = gs + loff[i];
    if (p == P - 1 && t == 0) off[n] = E;
    __syncthreads();
    for (int i = gs + t; i < ge; i += 256) {
        int2 rc = s8[i];
        int pos = gs + atomicAdd(&loff[rc.y - c0], 1);
        rows4[pos] = rc.x;
    }
}

// --- k1: t1 = concat(x,feat) @ W1 + b1 (persistent, W column in VGPRs) ---
__global__ __launch_bounds__(256, 4)
void k_linc(const float* __restrict__ x, const float* __restrict__ feat,
            const float* __restrict__ W, const float* __restrict__ b,
            float* __restrict__ out, int n, int nwaves) {
    __shared__ float sIn[4][FDIM];
    int t = threadIdx.x;
    int local = t >> 6, j = t & 63;
    float Wreg[FDIM];
    #pragma unroll
    for (int k = 0; k < FDIM; ++k) Wreg[k] = W[k * FDIM + j];   // column j
    float bj = b[j];
    int gw = blockIdx.x * 4 + local;
    for (int w = gw; w < n; w += nwaves) {
        sIn[local][j] = (j < 32) ? x[(size_t)w * 32 + j]
                                 : feat[(size_t)w * 32 + (j - 32)];
        __threadfence_block();
        float o = bj;
        #pragma unroll
        for (int k4 = 0; k4 < 16; ++k4) {
            float4 h4 = *(const float4*)&sIn[local][k4 * 4];
            o = fmaf(h4.x, Wreg[4 * k4 + 0], o);
            o = fmaf(h4.y, Wreg[4 * k4 + 1], o);
            o = fmaf(h4.z, Wreg[4 * k4 + 2], o);
            o = fmaf(h4.w, Wreg[4 * k4 + 3], o);
        }
        out[(size_t)w * FDIM + j] = o;
        __threadfence_block();   // order next iter's sIn write after reads
    }
}

// --- fused: out = [relu](relu(agg(h)) @ W + b), wave per node ---
template <bool RELU_OUT>
__global__ __launch_bounds__(256, 4)
void k_fused(const int* __restrict__ rows4, const int* __restrict__ off,
             const float* __restrict__ dis, const float* __restrict__ h,
             const float* __restrict__ W, const float* __restrict__ b,
             float* __restrict__ out, int n, int nwaves) {
    __shared__ float sIn[4][FDIM];
    int t = threadIdx.x;
    int local = t >> 6, j = t & 63;
    float Wreg[FDIM];
    #pragma unroll
    for (int k = 0; k < FDIM; ++k) Wreg[k] = W[k * FDIM + j];   // column j
    float bj = b[j];
    int gw = blockIdx.x * 4 + local;
    for (int w = gw; w < n; w += nwaves) {
        float dc = dis[w];
        float acc0 = dc * dc * h[(size_t)w * FDIM + j];   // self loop
        float acc1 = 0.0f;
        int k = off[w], e = off[w + 1];
        for (; k + 8 <= e; k += 8) {
            int r0 = rows4[k + 0], r1 = rows4[k + 1], r2 = rows4[k + 2], r3 = rows4[k + 3];
            int r4 = rows4[k + 4], r5 = rows4[k + 5], r6 = rows4[k + 6], r7 = rows4[k + 7];
            float h0 = h[(size_t)r0 * FDIM + j], h1 = h[(size_t)r1 * FDIM + j];
            float h2 = h[(size_t)r2 * FDIM + j], h3 = h[(size_t)r3 * FDIM + j];
            float h4 = h[(size_t)r4 * FDIM + j], h5 = h[(size_t)r5 * FDIM + j];
            float h6 = h[(size_t)r6 * FDIM + j], h7 = h[(size_t)r7 * FDIM + j];
            acc0 = fmaf(dis[r0] * dc, h0, acc0); acc1 = fmaf(dis[r1] * dc, h1, acc1);
            acc0 = fmaf(dis[r2] * dc, h2, acc0); acc1 = fmaf(dis[r3] * dc, h3, acc1);
            acc0 = fmaf(dis[r4] * dc, h4, acc0); acc1 = fmaf(dis[r5] * dc, h5, acc1);
            acc0 = fmaf(dis[r6] * dc, h6, acc0); acc1 = fmaf(dis[r7] * dc, h7, acc1);
        }
        for (; k + 2 <= e; k += 2) {
            int r0 = rows4[k], r1 = rows4[k + 1];
            acc0 = fmaf(dis[r0] * dc, h[(size_t)r0 * FDIM + j], acc0);
            acc1 = fmaf(dis[r1] * dc, h[(size_t)r1 * FDIM + j], acc1);
        }
        if (k < e) {
            int r = rows4[k];
            acc0 = fmaf(dis[r] * dc, h[(size_t)r * FDIM + j], acc0);
        }
        sIn[local][j] = fmaxf(acc0 + acc1, 0.0f);         // mid relu
        __threadfence_block();
        float o = bj;
        #pragma unroll
        for (int k4 = 0; k4 < 16; ++k4) {
            float4 h4 = *(const float4*)&sIn[local][k4 * 4];
            o = fmaf(h4.x, Wreg[4 * k4 + 0], o);
            o = fmaf(h4.y, Wreg[4 * k4 + 1], o);
            o = fmaf(h4.z, Wreg[4 * k4 + 2], o);
            o = fmaf(h4.w, Wreg[4 * k4 + 3], o);
        }
        if (RELU_OUT) o = fmaxf(o, 0.0f);
        out[(size_t)w * FDIM + j] = o;
        __threadfence_block();   // order next iter's sIn write after reads
    }
}

extern "C" void kernel_launch(void* const* d_in, const int* in_sizes, int n_in,
                              void* d_out, int out_size, void* d_ws, size_t ws_size,
                              hipStream_t stream) {
    const float* x    = (const float*)d_in[0];
    const float* feat = (const float*)d_in[1];
    const int*   ei   = (const int*)d_in[2];
    const float* W1   = (const float*)d_in[3];
    const float* b1   = (const float*)d_in[4];
    const float* W2   = (const float*)d_in[5];
    const float* b2   = (const float*)d_in[6];
    const float* Wfc  = (const float*)d_in[7];
    const float* bfc  = (const float*)d_in[8];
    float* out = (float*)d_out;

    const int n = in_sizes[0] / 32;   // 100000
    const int E = in_sizes[2] / 2;    // 1600000
    const int* row = ei;
    const int* col = ei + E;

    const int psize = (n + NPART - 1) / NPART;   // 12500
    const int P  = (n + BW - 1) / BW;            // 196
    const int CH = (E + NB - 1) / NB;            // 6250
    const int total = P * NB;                    // 50176
    const int nb1 = (total + 255) / 256;         // 196

    // ws layout identical to v4/v5
    int*   off  = (int*)d_ws;
    float* dis  = (float*)(off + (size_t)n + 1);
    int*   M    = (int*)(dis + n);
    int*   bsum = M + (size_t)total + 1;
    size_t co   = (size_t)n + 1 + n + total + 1 + 256;
    co += (co & 1);
    int2*  s8    = (int2*)((int*)d_ws + co);
    int*   rows4 = (int*)(s8 + E);
    float* bufA  = (float*)(rows4 + E);
    float* bufB  = bufA + (size_t)n * FDIM;
    unsigned* part = (unsigned*)bufA;            // consumed before bufA written

    const int B = 256;
    const int GP = 1024;                          // persistent blocks
    const int NW = GP * 4;                        // wave stride

    // dis (deg by row)
    k_deg<<<NPART * GPB, B, 0, stream>>>(row, part, E, n, psize);
    k_dis<<<(n + B - 1) / B, B, 0, stream>>>(part, dis, n, psize);
    // CSR by col
    k_chist<<<NB, B, 0, stream>>>(col, M, E, CH, P);
    k_s1<<<nb1, B, 0, stream>>>(M, bsum, total);
    k_s2<<<1, B, 0, stream>>>(bsum, nb1);
    k_s3<<<nb1, B, 0, stream>>>(M, bsum, total, E);
    k_cscatter<<<NB, B, 0, stream>>>(row, col, M, s8, E, CH, P);
    k_fsort<<<P, B, 0, stream>>>(s8, M, rows4, off, n, E, P);

    // t1 = concat@W1+b1 ; t2 = relu(agg(t1))@W2+b2 ; out = relu(relu(agg(t2))@Wfc+bfc)
    k_linc<<<GP, B, 0, stream>>>(x, feat, W1, b1, bufA, n, NW);
    k_fused<false><<<GP, B, 0, stream>>>(rows4, off, dis, bufA, W2, b2, bufB, n, NW);
    k_fused<true><<<GP, B, 0, stream>>>(rows4, off, dis, bufB, Wfc, bfc, out, n, NW);
}

// Round 8
// 392.435 us; speedup vs baseline: 2.0819x; 1.0388x over previous
//
#include <hip/hip_runtime.h>
#include <hip/hip_bf16.h>

// GCN v7 — fused gather+matvec; bf16 inter-layer activations (halves the
// random-gather line traffic, the measured bottleneck); GP doubled to 2048
// (round-7 occupancy was grid-limited at 39%). Accumulation/dis/W/output fp32.
//   build (counting-sort CSR by col, parallel scan): unchanged.
//   k_linc: t1(bf16) = concat(x,feat)@W1+b1
//   k_fused<false,true>:  t2(bf16) = relu(agg(t1))@W2+b2
//   k_fused<true,false>:  out(f32) = relu(relu(agg(t2))@Wfc+bfc)

#define FDIM 64
#define NPART 8
#define GPB 64
#define NB 256
#define BW 512
#define MAXP 1024

typedef __hip_bfloat16 bf16;

// --- degree histogram by row, LDS-partitioned ---
__global__ void k_deg(const int* __restrict__ row, unsigned* __restrict__ part,
                      int E, int n, int psize) {
    __shared__ unsigned sh[12512];
    int p = blockIdx.x / GPB;
    int g = blockIdx.x % GPB;
    int base = p * psize;
    int lim = n - base; if (lim > psize) lim = psize;
    for (int i = threadIdx.x; i < lim; i += blockDim.x) sh[i] = 0u;
    __syncthreads();
    int stride = GPB * blockDim.x;
    for (int e = g * blockDim.x + threadIdx.x; e < E; e += stride) {
        int r = row[e] - base;
        if ((unsigned)r < (unsigned)lim) atomicAdd(&sh[r], 1u);
    }
    __syncthreads();
    unsigned* dst = part + ((size_t)p * GPB + g) * psize;
    for (int i = threadIdx.x; i < lim; i += blockDim.x) dst[i] = sh[i];
}

__global__ void k_dis(const unsigned* __restrict__ part, float* __restrict__ dis,
                      int n, int psize) {
    int i = blockIdx.x * blockDim.x + threadIdx.x;
    if (i >= n) return;
    int p = i / psize, loc = i - p * psize;
    const unsigned* src = part + (size_t)p * GPB * psize + loc;
    unsigned s = 0;
    #pragma unroll 8
    for (int g = 0; g < GPB; ++g) s += src[(size_t)g * psize];
    dis[i] = rsqrtf((float)s + 1.0f);
}

// --- coarse histogram ---
__global__ void k_chist(const int* __restrict__ col, int* __restrict__ M,
                        int E, int CH, int P) {
    __shared__ int h[MAXP];
    int b = blockIdx.x;
    for (int i = threadIdx.x; i < P; i += blockDim.x) h[i] = 0;
    __syncthreads();
    int s = b * CH, e = min(s + CH, E);
    for (int i = s + threadIdx.x; i < e; i += blockDim.x)
        atomicAdd(&h[col[i] >> 9], 1);
    __syncthreads();
    for (int p = threadIdx.x; p < P; p += blockDim.x)
        M[p * NB + b] = h[p];
}

// --- 3-phase parallel exclusive scan ---
__global__ void k_s1(int* __restrict__ M, int* __restrict__ bsum, int total) {
    __shared__ int tmp[256];
    int t = threadIdx.x;
    int i = blockIdx.x * 256 + t;
    int v = (i < total) ? M[i] : 0;
    tmp[t] = v;
    __syncthreads();
    for (int d = 1; d < 256; d <<= 1) {
        int u = (t >= d) ? tmp[t - d] : 0;
        __syncthreads();
        tmp[t] += u;
        __syncthreads();
    }
    if (i < total) M[i] = tmp[t] - v;
    if (t == 255) bsum[blockIdx.x] = tmp[255];
}

__global__ void k_s2(int* __restrict__ bsum, int nb) {
    __shared__ int tmp[256];
    int t = threadIdx.x;
    int v = (t < nb) ? bsum[t] : 0;
    tmp[t] = v;
    __syncthreads();
    for (int d = 1; d < 256; d <<= 1) {
        int u = (t >= d) ? tmp[t - d] : 0;
        __syncthreads();
        tmp[t] += u;
        __syncthreads();
    }
    if (t < nb) bsum[t] = tmp[t] - v;
}

__global__ void k_s3(int* __restrict__ M, const int* __restrict__ bsum,
                     int total, int E) {
    int i = blockIdx.x * 256 + threadIdx.x;
    if (i < total) M[i] += bsum[blockIdx.x];
    if (i == 0) M[total] = E;
}

// --- deterministic coarse scatter ---
__global__ void k_cscatter(const int* __restrict__ row, const int* __restrict__ col,
                           const int* __restrict__ M, int2* __restrict__ s8,
                           int E, int CH, int P) {
    __shared__ int cur[MAXP];
    int b = blockIdx.x;
    for (int p = threadIdx.x; p < P; p += blockDim.x) cur[p] = M[p * NB + b];
    __syncthreads();
    int s = b * CH, e = min(s + CH, E);
    for (int i = s + threadIdx.x; i < e; i += blockDim.x) {
        int r = row[i], c = col[i];
        int pos = atomicAdd(&cur[c >> 9], 1);
        s8[pos] = make_int2(r, c);
    }
}

// --- fine sort -> off[n+1], rows4[E] ---
__global__ void k_fsort(const int2* __restrict__ s8, const int* __restrict__ M,
                        int* __restrict__ rows4, int* __restrict__ off,
                        int n, int E, int P) {
    __shared__ int hist[BW];
    __shared__ int loff[BW];
    __shared__ int tmp[256];
    int p = blockIdx.x, t = threadIdx.x;
    int gs = M[p * NB];
    int ge = (p + 1 < P) ? M[(p + 1) * NB] : E;
    int c0 = p << 9;
    int lim = n - c0; if (lim > BW) lim = BW;
    hist[2 * t] = 0; hist[2 * t + 1] = 0;
    __syncthreads();
    for (int i = gs + t; i < ge; i += 256)
        atomicAdd(&hist[s8[i].y - c0], 1);
    __syncthreads();
    int s0 = hist[2 * t], s1 = hist[2 * t + 1];
    int ps = s0 + s1;
    tmp[t] = ps;
    __syncthreads();
    for (int d = 1; d < 256; d <<= 1) {
        int u = (t >= d) ? tmp[t - d] : 0;
        __syncthreads();
        tmp[t] += u;
        __syncthreads();
    }
    int ex = tmp[t] - ps;
    loff[2 * t] = ex;
    loff[2 * t + 1] = ex + s0;
    __syncthreads();
    for (int i = t; i < lim; i += 256) off[c0 + i] = gs + loff[i];
    if (p == P - 1 && t == 0) off[n] = E;
    __syncthreads();
    for (int i = gs + t; i < ge; i += 256) {
        int2 rc = s8[i];
        int pos = gs + atomicAdd(&loff[rc.y - c0], 1);
        rows4[pos] = rc.x;
    }
}

// --- k1: t1(bf16) = concat(x,feat) @ W1 + b1 ---
__global__ __launch_bounds__(256, 4)
void k_linc(const float* __restrict__ x, const float* __restrict__ feat,
            const float* __restrict__ W, const float* __restrict__ b,
            bf16* __restrict__ out, int n, int nwaves) {
    __shared__ float sIn[4][FDIM];
    int t = threadIdx.x;
    int local = t >> 6, j = t & 63;
    float Wreg[FDIM];
    #pragma unroll
    for (int k = 0; k < FDIM; ++k) Wreg[k] = W[k * FDIM + j];   // column j
    float bj = b[j];
    int gw = blockIdx.x * 4 + local;
    for (int w = gw; w < n; w += nwaves) {
        sIn[local][j] = (j < 32) ? x[(size_t)w * 32 + j]
                                 : feat[(size_t)w * 32 + (j - 32)];
        __threadfence_block();
        float o = bj;
        #pragma unroll
        for (int k4 = 0; k4 < 16; ++k4) {
            float4 h4 = *(const float4*)&sIn[local][k4 * 4];
            o = fmaf(h4.x, Wreg[4 * k4 + 0], o);
            o = fmaf(h4.y, Wreg[4 * k4 + 1], o);
            o = fmaf(h4.z, Wreg[4 * k4 + 2], o);
            o = fmaf(h4.w, Wreg[4 * k4 + 3], o);
        }
        out[(size_t)w * FDIM + j] = __float2bfloat16(o);
        __threadfence_block();
    }
}

// --- fused: out = [relu](relu(agg(h)) @ W + b), wave per node, h in bf16 ---
template <bool RELU_OUT, bool OUT_BF16>
__global__ __launch_bounds__(256, 4)
void k_fused(const int* __restrict__ rows4, const int* __restrict__ off,
             const float* __restrict__ dis, const bf16* __restrict__ h,
             const float* __restrict__ W, const float* __restrict__ b,
             void* __restrict__ outp, int n, int nwaves) {
    __shared__ float sIn[4][FDIM];
    int t = threadIdx.x;
    int local = t >> 6, j = t & 63;
    float Wreg[FDIM];
    #pragma unroll
    for (int k = 0; k < FDIM; ++k) Wreg[k] = W[k * FDIM + j];   // column j
    float bj = b[j];
    int gw = blockIdx.x * 4 + local;
    for (int w = gw; w < n; w += nwaves) {
        float dc = dis[w];
        float acc0 = dc * dc * __bfloat162float(h[(size_t)w * FDIM + j]);
        float acc1 = 0.0f;
        int k = off[w], e = off[w + 1];
        for (; k + 8 <= e; k += 8) {
            int r0 = rows4[k + 0], r1 = rows4[k + 1], r2 = rows4[k + 2], r3 = rows4[k + 3];
            int r4 = rows4[k + 4], r5 = rows4[k + 5], r6 = rows4[k + 6], r7 = rows4[k + 7];
            float h0 = __bfloat162float(h[(size_t)r0 * FDIM + j]);
            float h1 = __bfloat162float(h[(size_t)r1 * FDIM + j]);
            float h2 = __bfloat162float(h[(size_t)r2 * FDIM + j]);
            float h3 = __bfloat162float(h[(size_t)r3 * FDIM + j]);
            float h4 = __bfloat162float(h[(size_t)r4 * FDIM + j]);
            float h5 = __bfloat162float(h[(size_t)r5 * FDIM + j]);
            float h6 = __bfloat162float(h[(size_t)r6 * FDIM + j]);
            float h7 = __bfloat162float(h[(size_t)r7 * FDIM + j]);
            acc0 = fmaf(dis[r0] * dc, h0, acc0); acc1 = fmaf(dis[r1] * dc, h1, acc1);
            acc0 = fmaf(dis[r2] * dc, h2, acc0); acc1 = fmaf(dis[r3] * dc, h3, acc1);
            acc0 = fmaf(dis[r4] * dc, h4, acc0); acc1 = fmaf(dis[r5] * dc, h5, acc1);
            acc0 = fmaf(dis[r6] * dc, h6, acc0); acc1 = fmaf(dis[r7] * dc, h7, acc1);
        }
        for (; k + 2 <= e; k += 2) {
            int r0 = rows4[k], r1 = rows4[k + 1];
            acc0 = fmaf(dis[r0] * dc, __bfloat162float(h[(size_t)r0 * FDIM + j]), acc0);
            acc1 = fmaf(dis[r1] * dc, __bfloat162float(h[(size_t)r1 * FDIM + j]), acc1);
        }
        if (k < e) {
            int r = rows4[k];
            acc0 = fmaf(dis[r] * dc, __bfloat162float(h[(size_t)r * FDIM + j]), acc0);
        }
        sIn[local][j] = fmaxf(acc0 + acc1, 0.0f);         // mid relu
        __threadfence_block();
        float o = bj;
        #pragma unroll
        for (int k4 = 0; k4 < 16; ++k4) {
            float4 h4 = *(const float4*)&sIn[local][k4 * 4];
            o = fmaf(h4.x, Wreg[4 * k4 + 0], o);
            o = fmaf(h4.y, Wreg[4 * k4 + 1], o);
            o = fmaf(h4.z, Wreg[4 * k4 + 2], o);
            o = fmaf(h4.w, Wreg[4 * k4 + 3], o);
        }
        if (RELU_OUT) o = fmaxf(o, 0.0f);
        if (OUT_BF16) ((bf16*)outp)[(size_t)w * FDIM + j] = __float2bfloat16(o);
        else          ((float*)outp)[(size_t)w * FDIM + j] = o;
        __threadfence_block();
    }
}

extern "C" void kernel_launch(void* const* d_in, const int* in_sizes, int n_in,
                              void* d_out, int out_size, void* d_ws, size_t ws_size,
                              hipStream_t stream) {
    const float* x    = (const float*)d_in[0];
    const float* feat = (const float*)d_in[1];
    const int*   ei   = (const int*)d_in[2];
    const float* W1   = (const float*)d_in[3];
    const float* b1   = (const float*)d_in[4];
    const float* W2   = (const float*)d_in[5];
    const float* b2   = (const float*)d_in[6];
    const float* Wfc  = (const float*)d_in[7];
    const float* bfc  = (const float*)d_in[8];
    float* out = (float*)d_out;

    const int n = in_sizes[0] / 32;   // 100000
    const int E = in_sizes[2] / 2;    // 1600000
    const int* row = ei;
    const int* col = ei + E;

    const int psize = (n + NPART - 1) / NPART;   // 12500
    const int P  = (n + BW - 1) / BW;            // 196
    const int CH = (E + NB - 1) / NB;            // 6250
    const int total = P * NB;                    // 50176
    const int nb1 = (total + 255) / 256;         // 196

    // ws (ints): off[n+1] | dis[n] | M[total+1] | bsum[256] | pad | s8[2E] |
    //            rows4[E] | bufA(bf16 64n) | bufB(bf16 64n)
    // part (NPART*GPB*psize u32 = 25.6 MB) aliases bufA+bufB (25.6 MB, consumed
    // by k_dis before any buf is written).
    int*   off  = (int*)d_ws;
    float* dis  = (float*)(off + (size_t)n + 1);
    int*   M    = (int*)(dis + n);
    int*   bsum = M + (size_t)total + 1;
    size_t co   = (size_t)n + 1 + n + total + 1 + 256;
    co += (co & 1);
    int2*  s8    = (int2*)((int*)d_ws + co);
    int*   rows4 = (int*)(s8 + E);
    bf16*  bufA  = (bf16*)(rows4 + E);
    bf16*  bufB  = bufA + (size_t)n * FDIM;
    unsigned* part = (unsigned*)bufA;            // consumed before bufs written

    const int B = 256;
    const int GP = 2048;                          // persistent blocks (full occ.)
    const int NW = GP * 4;                        // wave stride

    // dis (deg by row)
    k_deg<<<NPART * GPB, B, 0, stream>>>(row, part, E, n, psize);
    k_dis<<<(n + B - 1) / B, B, 0, stream>>>(part, dis, n, psize);
    // CSR by col
    k_chist<<<NB, B, 0, stream>>>(col, M, E, CH, P);
    k_s1<<<nb1, B, 0, stream>>>(M, bsum, total);
    k_s2<<<1, B, 0, stream>>>(bsum, nb1);
    k_s3<<<nb1, B, 0, stream>>>(M, bsum, total, E);
    k_cscatter<<<NB, B, 0, stream>>>(row, col, M, s8, E, CH, P);
    k_fsort<<<P, B, 0, stream>>>(s8, M, rows4, off, n, E, P);

    // t1 = concat@W1+b1 ; t2 = relu(agg(t1))@W2+b2 ; out = relu(relu(agg(t2))@Wfc+bfc)
    k_linc<<<GP, B, 0, stream>>>(x, feat, W1, b1, bufA, n, NW);
    k_fused<false, true><<<GP, B, 0, stream>>>(rows4, off, dis, bufA, W2, b2, bufB, n, NW);
    k_fused<true, false><<<GP, B, 0, stream>>>(rows4, off, dis, bufB, Wfc, bfc, out, n, NW);
}